// Round 3
// baseline (228.290 us; speedup 1.0000x reference)
//
#include <hip/hip_runtime.h>

typedef unsigned short u16;
typedef __attribute__((ext_vector_type(8))) short short8;
typedef __attribute__((ext_vector_type(8))) unsigned short ushort8_t;
typedef __attribute__((ext_vector_type(4))) float f32x4;

#define BATCH   16
#define CCH     512
#define NBOX    36
#define SS      26
#define INDIM   25088   // 512*49
#define HIDN    512
#define M_ROWS  576     // BATCH*NBOX
#define KSPLIT  28
#define KITERS  14      // per split, BK=64 -> 28*14*64 = 25088

__device__ __forceinline__ u16 f2bf(float f) {
  unsigned u = __float_as_uint(f);
  u += 0x7FFF + ((u >> 16) & 1);   // RNE
  return (u16)(u >> 16);
}
__device__ __forceinline__ float bf2f(u16 h) {
  return __uint_as_float(((unsigned)h) << 16);
}

typedef __attribute__((address_space(3))) void* as3_ptr;
typedef const __attribute__((address_space(1))) void* as1_cptr;
__device__ __forceinline__ void gload_lds16(const void* g, void* l) {
  __builtin_amdgcn_global_load_lds((as1_cptr)g, (as3_ptr)l, 16, 0, 0);
}

// ---------------- kernel 1: transpose lf (B,C,H,W) f32 -> (B,HW,C) bf16 ----
__global__ __launch_bounds__(256) void k_transpose_lf(const float* __restrict__ in,
                                                      u16* __restrict__ out) {
  __shared__ float t[32][33];
  int b = blockIdx.z, ct = blockIdx.y, pt = blockIdx.x;
  int tx = threadIdx.x, ty = threadIdx.y;
#pragma unroll
  for (int i = 0; i < 4; ++i) {
    int c = ct * 32 + ty + i * 8;
    int p = pt * 32 + tx;
    t[ty + i * 8][tx] = in[((size_t)b * CCH + c) * 1024 + p];
  }
  __syncthreads();
#pragma unroll
  for (int i = 0; i < 4; ++i) {
    int p = pt * 32 + ty + i * 8;
    int c = ct * 32 + tx;
    out[((size_t)b * 1024 + p) * CCH + c] = f2bf(t[tx][ty + i * 8]);
  }
}

// ---------------- kernel 2: roi_fc_W f32 -> bf16 ---------------------------
__global__ __launch_bounds__(256) void k_convert_w(const float4* __restrict__ in,
                                                   ushort4* __restrict__ out) {
  int i = blockIdx.x * 256 + threadIdx.x;   // grid sized exactly
  float4 v = in[i];
  ushort4 o;
  o.x = f2bf(v.x); o.y = f2bf(v.y); o.z = f2bf(v.z); o.w = f2bf(v.w);
  out[i] = o;
}

// ---------------- kernel 3: ROI align -> flat (576, 25088) bf16 ------------
// v2: thread = (cg = tid&63 -> 8 contiguous channels, pg = tid>>6 -> pixel
// stripe). 16B ushort8 loads, 8-float acc per pixel that dies each iteration
// -> no VGPR spill (v1 spilled ~108 MB of scratch to HBM).
__global__ __launch_bounds__(512) void k_roi(const u16* __restrict__ lf_t,
                                             const float* __restrict__ pred,
                                             u16* __restrict__ flat) {
  __shared__ int   s_ylo[14], s_yhi[14], s_xlo[14], s_xhi[14];
  __shared__ float s_wyl[14], s_wyh[14], s_wxl[14], s_wxh[14];
  __shared__ u16   s_out[INDIM];   // 50176 B

  int blk = blockIdx.x;
  int b = blk / NBOX, n = blk % NBOX;
  int t = threadIdx.x;

  if (t < 28) {
    bool isY = t < 14;
    int j = isY ? t : t - 14;
    float c0, c1, c2, c3;
    if (n < SS) {
      const float* p = pred + ((size_t)(b * SS + n)) * 4;
      c0 = p[0]; c1 = p[1]; c2 = p[2]; c3 = p[3];
    } else { c0 = 0.f; c1 = 0.f; c2 = 1.f; c3 = 1.f; }
    float lo1 = (isY ? c1 : c0) * 32.f;
    float hi1 = (isY ? c3 : c2) * 32.f;
    float sz = fmaxf(hi1 - lo1, 1.f);
    float bs = sz * (1.f / 7.f);
    float off = (float)(j >> 1) + 0.25f + 0.5f * (float)(j & 1);
    float pos = lo1 + off * bs;
    bool valid = (pos > -1.f) && (pos < 32.f);
    float tc = fminf(fmaxf(pos, 0.f), 31.f);
    int lo = (int)floorf(tc);
    int hi = min(lo + 1, 31);
    float fr = tc - (float)lo;
    float wl = valid ? (1.f - fr) : 0.f;
    float wh = valid ? fr : 0.f;
    if (isY) { s_ylo[j] = lo; s_yhi[j] = hi; s_wyl[j] = wl; s_wyh[j] = wh; }
    else     { s_xlo[j] = lo; s_xhi[j] = hi; s_wxl[j] = wl; s_wxh[j] = wh; }
  }
  __syncthreads();

  int cg = t & 63;          // channel group: channels cg*8 .. cg*8+7
  int pg = t >> 6;          // pixel stripe: pixels pg, pg+8, ...
  const u16* base = lf_t + (size_t)b * 1024 * CCH + cg * 8;

  for (int p = pg; p < 49; p += 8) {
    int py = p / 7, px = p % 7;
    float a0 = 0.f, a1 = 0.f, a2 = 0.f, a3 = 0.f;
    float a4 = 0.f, a5 = 0.f, a6 = 0.f, a7 = 0.f;
#pragma unroll
    for (int sy = 0; sy < 2; ++sy) {
      int jy = 2 * py + sy;
      const u16* rlo = base + s_ylo[jy] * 32 * CCH;
      const u16* rhi = base + s_yhi[jy] * 32 * CCH;
      float wyl = s_wyl[jy], wyh = s_wyh[jy];
#pragma unroll
      for (int sx = 0; sx < 2; ++sx) {
        int jx = 2 * px + sx;
        int xl = s_xlo[jx] * CCH, xh = s_xhi[jx] * CCH;
        float wll = wyl * s_wxl[jx], wlh = wyl * s_wxh[jx];
        float whl = wyh * s_wxl[jx], whh = wyh * s_wxh[jx];
        ushort8_t vll = *(const ushort8_t*)(rlo + xl);
        ushort8_t vlh = *(const ushort8_t*)(rlo + xh);
        ushort8_t vhl = *(const ushort8_t*)(rhi + xl);
        ushort8_t vhh = *(const ushort8_t*)(rhi + xh);
        a0 += wll * bf2f(vll[0]) + wlh * bf2f(vlh[0]) + whl * bf2f(vhl[0]) + whh * bf2f(vhh[0]);
        a1 += wll * bf2f(vll[1]) + wlh * bf2f(vlh[1]) + whl * bf2f(vhl[1]) + whh * bf2f(vhh[1]);
        a2 += wll * bf2f(vll[2]) + wlh * bf2f(vlh[2]) + whl * bf2f(vhl[2]) + whh * bf2f(vhh[2]);
        a3 += wll * bf2f(vll[3]) + wlh * bf2f(vlh[3]) + whl * bf2f(vhl[3]) + whh * bf2f(vhh[3]);
        a4 += wll * bf2f(vll[4]) + wlh * bf2f(vlh[4]) + whl * bf2f(vhl[4]) + whh * bf2f(vhh[4]);
        a5 += wll * bf2f(vll[5]) + wlh * bf2f(vlh[5]) + whl * bf2f(vhl[5]) + whh * bf2f(vhh[5]);
        a6 += wll * bf2f(vll[6]) + wlh * bf2f(vlh[6]) + whl * bf2f(vhl[6]) + whh * bf2f(vhh[6]);
        a7 += wll * bf2f(vll[7]) + wlh * bf2f(vlh[7]) + whl * bf2f(vhl[7]) + whh * bf2f(vhh[7]);
      }
    }
    int c0i = cg * 8;
    s_out[(c0i + 0) * 49 + p] = f2bf(a0 * 0.25f);
    s_out[(c0i + 1) * 49 + p] = f2bf(a1 * 0.25f);
    s_out[(c0i + 2) * 49 + p] = f2bf(a2 * 0.25f);
    s_out[(c0i + 3) * 49 + p] = f2bf(a3 * 0.25f);
    s_out[(c0i + 4) * 49 + p] = f2bf(a4 * 0.25f);
    s_out[(c0i + 5) * 49 + p] = f2bf(a5 * 0.25f);
    s_out[(c0i + 6) * 49 + p] = f2bf(a6 * 0.25f);
    s_out[(c0i + 7) * 49 + p] = f2bf(a7 * 0.25f);
  }
  __syncthreads();

  uint4* dst = (uint4*)(flat + (size_t)blk * INDIM);
  const uint4* src = (const uint4*)s_out;
  for (int i = t; i < INDIM / 8; i += 512) dst[i] = src[i];
}

// ---------------- kernel 4: GEMM 576(+pad)x512xK, split-K, bf16 MFMA -------
// v2: XOR-swizzled LDS layout. Physical chunk row*8+pc holds logical column
// pc ^ (row&7); permutation applied on the GLOBAL side of global_load_lds
// (its LDS dest must stay lane-contiguous). Fragment reads then spread the 16
// rows of a quad across all 8 bank groups -> 2 lanes/bank = conflict-free
// (v1: 16-way conflict, SQ_LDS_BANK_CONFLICT=6.02M, ~12 extra cyc/ds_read).
__global__ __launch_bounds__(256) void k_gemm(const u16* __restrict__ flat,
                                              const u16* __restrict__ Wb,
                                              float* __restrict__ partials) {
  __shared__ u16 As[128 * 64];
  __shared__ u16 Bs[128 * 64];

  int tid = threadIdx.x;
  int wave = tid >> 6, lane = tid & 63;
  int wm = wave >> 1, wn = wave & 1;
  int quad = lane >> 4, r = lane & 15;
  int xb = r & 7;                       // read-side XOR key

  int tileM0 = blockIdx.y * 128;
  int tileN0 = blockIdx.x * 128;
  int kbase = blockIdx.z * (KITERS * 64);

  f32x4 acc[4][4];
#pragma unroll
  for (int mi = 0; mi < 4; ++mi)
#pragma unroll
    for (int ni = 0; ni < 4; ++ni) acc[mi][ni] = (f32x4){0.f, 0.f, 0.f, 0.f};

  for (int kt = 0; kt < KITERS; ++kt) {
    int k0 = kbase + kt * 64;
#pragma unroll
    for (int t = 0; t < 4; ++t) {
      int chunk = (wave * 4 + t) * 64 + lane;
      int row = chunk >> 3;
      int pcol = chunk & 7;
      int lcol = ((pcol ^ (row & 7)) << 3);   // logical k-offset (u16 units)
      int grow = min(tileM0 + row, M_ROWS - 1);   // clamp M tail
      gload_lds16(flat + (size_t)grow * INDIM + k0 + lcol,
                  &As[(wave * 4 + t) * 512]);
      int nrow = tileN0 + row;
      gload_lds16(Wb + (size_t)nrow * INDIM + k0 + lcol,
                  &Bs[(wave * 4 + t) * 512]);
    }
    __syncthreads();

#pragma unroll
    for (int kk = 0; kk < 64; kk += 32) {
      int k8 = kk >> 3;                 // 0 or 4
      int pc = ((k8 + quad) ^ xb) << 3; // physical column (u16 units)
      short8 af[4], bfr[4];
#pragma unroll
      for (int mi = 0; mi < 4; ++mi)
        af[mi] = *(const short8*)&As[(wm * 64 + mi * 16 + r) * 64 + pc];
#pragma unroll
      for (int ni = 0; ni < 4; ++ni)
        bfr[ni] = *(const short8*)&Bs[(wn * 64 + ni * 16 + r) * 64 + pc];
#pragma unroll
      for (int mi = 0; mi < 4; ++mi)
#pragma unroll
        for (int ni = 0; ni < 4; ++ni)
          acc[mi][ni] = __builtin_amdgcn_mfma_f32_16x16x32_bf16(
              af[mi], bfr[ni], acc[mi][ni], 0, 0, 0);
    }
    __syncthreads();
  }

  float* part = partials + (size_t)blockIdx.z * (M_ROWS * HIDN);
#pragma unroll
  for (int mi = 0; mi < 4; ++mi)
#pragma unroll
    for (int ni = 0; ni < 4; ++ni) {
      int row0 = tileM0 + wm * 64 + mi * 16 + quad * 4;
      int col = tileN0 + wn * 64 + ni * 16 + r;
#pragma unroll
      for (int reg = 0; reg < 4; ++reg) {
        int row = row0 + reg;
        if (row < M_ROWS) part[(size_t)row * HIDN + col] = acc[mi][ni][reg];
      }
    }
}

// ---------------- kernel 5: reduce split-K + bias + relu -> feats f32 ------
__global__ __launch_bounds__(256) void k_reduce(const float* __restrict__ partials,
                                                const float* __restrict__ bias,
                                                float* __restrict__ feats) {
  int gid = blockIdx.x * 256 + threadIdx.x;   // < 576*512
  int h = gid & (HIDN - 1);
  float s = 0.f;
#pragma unroll
  for (int k = 0; k < KSPLIT; ++k) s += partials[(size_t)k * (M_ROWS * HIDN) + gid];
  s += bias[h];
  feats[gid] = fmaxf(s, 0.f);
}

// ---------------- kernel 6: all heads, one wave per output dot -------------
__device__ __forceinline__ float wave_red(float s) {
#pragma unroll
  for (int off = 32; off > 0; off >>= 1) s += __shfl_down(s, off);
  return s;
}

__global__ __launch_bounds__(256) void k_heads(const float* __restrict__ feats,
                                               const float* __restrict__ pred,
                                               const float* __restrict__ cW,
                                               const float* __restrict__ cb,
                                               const float* __restrict__ pW,
                                               const float* __restrict__ pb,
                                               const float* __restrict__ lW,
                                               const float* __restrict__ lb,
                                               const float* __restrict__ gW,
                                               const float* __restrict__ gb,
                                               const int* __restrict__ lidx,
                                               const int* __restrict__ gidx,
                                               float* __restrict__ out) {
  int wid = blockIdx.x * 4 + (threadIdx.x >> 6);   // 0..4639
  int lane = threadIdx.x & 63;
  float sum = 0.f;

  if (wid < 1664) {                 // refined (B,26,4)
    int b = wid / 104, rr = wid % 104, s = rr >> 2, o = rr & 3;
    const float* f = feats + (size_t)(b * NBOX + s) * HIDN;
    const float* w = cW + (size_t)(s * 4 + o) * HIDN;
#pragma unroll
    for (int i = 0; i < 8; ++i) sum += f[lane + i * 64] * w[lane + i * 64];
    sum = wave_red(sum);
    if (lane == 0) {
      const float* p = pred + (size_t)(b * SS + s) * 4;
      float wdt = p[2] - p[0], hgt = p[3] - p[1];
      float whv = (o & 1) ? hgt : wdt;
      out[wid] = p[o] + (sum + cb[s * 4 + o]) * whv;
    }
  } else if (wid < 2080) {          // presence (B,26)
    int i = wid - 1664;
    int b = i / 26, s = i % 26;
    const float* f = feats + (size_t)(b * NBOX + s) * HIDN;
    const float* w = pW + (size_t)s * HIDN;
#pragma unroll
    for (int k = 0; k < 8; ++k) sum += f[lane + k * 64] * w[lane + k * 64];
    sum = wave_red(sum);
    if (lane == 0) out[1664 + i] = sum + pb[s];
  } else if (wid < 3616) {          // loc (B,12,8)
    int i = wid - 2080;
    int b = i / 96, rr = i % 96, l = rr >> 3, o = rr & 7;
    const float* f = feats + (size_t)(b * NBOX + lidx[l]) * HIDN;
    const float* w = lW + (size_t)(l * 8 + o) * HIDN;
#pragma unroll
    for (int k = 0; k < 8; ++k) sum += f[lane + k * 64] * w[lane + k * 64];
    sum = wave_red(sum);
    if (lane == 0) out[2080 + b * 160 + rr] = sum + lb[l * 8 + o];
  } else {                          // grp (B,4,16), K = 6*512
    int i = wid - 3616;
    int b = i / 64, rr = i % 64, g = rr >> 4, o = rr & 15;
    const float* w = gW + (size_t)(g * 16 + o) * 3072;
#pragma unroll
    for (int jj = 0; jj < 6; ++jj) {
      const float* f = feats + (size_t)(b * NBOX + gidx[g * 6 + jj]) * HIDN;
      const float* wj = w + jj * 512;
#pragma unroll
      for (int k = 0; k < 8; ++k) sum += f[lane + k * 64] * wj[lane + k * 64];
    }
    sum = wave_red(sum);
    if (lane == 0) out[2080 + b * 160 + 96 + rr] = sum + gb[g * 16 + o];
  }
}

// ---------------------------------------------------------------------------
extern "C" void kernel_launch(void* const* d_in, const int* in_sizes, int n_in,
                              void* d_out, int out_size, void* d_ws, size_t ws_size,
                              hipStream_t stream) {
  const float* lf      = (const float*)d_in[0];
  const float* pred    = (const float*)d_in[1];
  const float* roiW    = (const float*)d_in[2];
  const float* roiB    = (const float*)d_in[3];
  const float* cW      = (const float*)d_in[4];
  const float* cb      = (const float*)d_in[5];
  const float* pW      = (const float*)d_in[6];
  const float* pb      = (const float*)d_in[7];
  const float* lW      = (const float*)d_in[8];
  const float* lb      = (const float*)d_in[9];
  const float* gW      = (const float*)d_in[10];
  const float* gb      = (const float*)d_in[11];
  const int*   lidx    = (const int*)d_in[12];
  const int*   gidx    = (const int*)d_in[13];
  float* out = (float*)d_out;

  char* ws = (char*)d_ws;
  // region 0: lf_t (16.8 MB) then reused by partials (33.0 MB) after k_roi
  u16*   lf_t     = (u16*)ws;
  float* partials = (float*)ws;
  u16*   Wb   = (u16*)(ws + 33030144);                 // 25,690,112 B
  u16*   flat = (u16*)(ws + 33030144 + 25690112);      // 28,901,376 B
  float* feats = (float*)(ws + 33030144 + 25690112 + 28901376); // 1,179,648 B

  k_transpose_lf<<<dim3(32, 16, 16), dim3(32, 8), 0, stream>>>(lf, lf_t);
  k_convert_w<<<12544, 256, 0, stream>>>((const float4*)roiW, (ushort4*)Wb);
  k_roi<<<576, 512, 0, stream>>>(lf_t, pred, flat);
  // NOTE: partials aliases lf_t's region; k_roi (last reader of lf_t) is
  // stream-ordered before k_gemm (first writer of partials).
  k_gemm<<<dim3(4, 5, KSPLIT), 256, 0, stream>>>(flat, Wb, partials);
  k_reduce<<<(M_ROWS * HIDN) / 256, 256, 0, stream>>>(partials, roiB, feats);
  k_heads<<<1160, 256, 0, stream>>>(feats, pred, cW, cb, pW, pb, lW, lb, gW, gb,
                                    lidx, gidx, out);
}

// Round 4
// 225.178 us; speedup vs baseline: 1.0138x; 1.0138x over previous
//
#include <hip/hip_runtime.h>

typedef unsigned short u16;
typedef __attribute__((ext_vector_type(8))) short short8;
typedef __attribute__((ext_vector_type(8))) unsigned short ushort8_t;
typedef __attribute__((ext_vector_type(4))) float f32x4;
typedef __attribute__((ext_vector_type(2))) float v2f;

#define BATCH   16
#define CCH     512
#define NBOX    36
#define SS      26
#define INDIM   25088   // 512*49
#define HIDN    512
#define M_ROWS  576     // BATCH*NBOX
#define KSPLIT  28
#define KITERS  14      // per split, BK=64 -> 28*14*64 = 25088

__device__ __forceinline__ u16 f2bf(float f) {
  unsigned u = __float_as_uint(f);
  u += 0x7FFF + ((u >> 16) & 1);   // RNE
  return (u16)(u >> 16);
}
__device__ __forceinline__ float bf2f(u16 h) {
  return __uint_as_float(((unsigned)h) << 16);
}
__device__ __forceinline__ v2f bf2x2(u16 a, u16 b) {
  v2f r;
  r.x = __uint_as_float(((unsigned)a) << 16);
  r.y = __uint_as_float(((unsigned)b) << 16);
  return r;
}

typedef __attribute__((address_space(3))) void* as3_ptr;
typedef const __attribute__((address_space(1))) void* as1_cptr;
__device__ __forceinline__ void gload_lds16(const void* g, void* l) {
  __builtin_amdgcn_global_load_lds((as1_cptr)g, (as3_ptr)l, 16, 0, 0);
}

// ---------------- kernel 1: transpose lf (B,C,H,W) f32 -> (B,HW,C) bf16 ----
__global__ __launch_bounds__(256) void k_transpose_lf(const float* __restrict__ in,
                                                      u16* __restrict__ out) {
  __shared__ float t[32][33];
  int b = blockIdx.z, ct = blockIdx.y, pt = blockIdx.x;
  int tx = threadIdx.x, ty = threadIdx.y;
#pragma unroll
  for (int i = 0; i < 4; ++i) {
    int c = ct * 32 + ty + i * 8;
    int p = pt * 32 + tx;
    t[ty + i * 8][tx] = in[((size_t)b * CCH + c) * 1024 + p];
  }
  __syncthreads();
#pragma unroll
  for (int i = 0; i < 4; ++i) {
    int p = pt * 32 + ty + i * 8;
    int c = ct * 32 + tx;
    out[((size_t)b * 1024 + p) * CCH + c] = f2bf(t[tx][ty + i * 8]);
  }
}

// ---------------- kernel 2: roi_fc_W f32 -> bf16 ---------------------------
__global__ __launch_bounds__(256) void k_convert_w(const float4* __restrict__ in,
                                                   ushort4* __restrict__ out) {
  int i = blockIdx.x * 256 + threadIdx.x;   // grid sized exactly
  float4 v = in[i];
  ushort4 o;
  o.x = f2bf(v.x); o.y = f2bf(v.y); o.z = f2bf(v.z); o.w = f2bf(v.w);
  out[i] = o;
}

// ---------------- kernel 3: ROI align -> flat (576, 25088) bf16 ------------
// v3: v2f (packed-f32) accumulation -> v_pk_fma_f32, halves VALU issue of the
// interpolation inner loop. Thread = (cg: 8 contiguous channels, pg: pixel
// stripe); 16B ushort8 tap loads; no VGPR spill.
__global__ __launch_bounds__(512) void k_roi(const u16* __restrict__ lf_t,
                                             const float* __restrict__ pred,
                                             u16* __restrict__ flat) {
  __shared__ int   s_ylo[14], s_yhi[14], s_xlo[14], s_xhi[14];
  __shared__ float s_wyl[14], s_wyh[14], s_wxl[14], s_wxh[14];
  __shared__ u16   s_out[INDIM];   // 50176 B

  int blk = blockIdx.x;
  int b = blk / NBOX, n = blk % NBOX;
  int t = threadIdx.x;

  if (t < 28) {
    bool isY = t < 14;
    int j = isY ? t : t - 14;
    float c0, c1, c2, c3;
    if (n < SS) {
      const float* p = pred + ((size_t)(b * SS + n)) * 4;
      c0 = p[0]; c1 = p[1]; c2 = p[2]; c3 = p[3];
    } else { c0 = 0.f; c1 = 0.f; c2 = 1.f; c3 = 1.f; }
    float lo1 = (isY ? c1 : c0) * 32.f;
    float hi1 = (isY ? c3 : c2) * 32.f;
    float sz = fmaxf(hi1 - lo1, 1.f);
    float bs = sz * (1.f / 7.f);
    float off = (float)(j >> 1) + 0.25f + 0.5f * (float)(j & 1);
    float pos = lo1 + off * bs;
    bool valid = (pos > -1.f) && (pos < 32.f);
    float tc = fminf(fmaxf(pos, 0.f), 31.f);
    int lo = (int)floorf(tc);
    int hi = min(lo + 1, 31);
    float fr = tc - (float)lo;
    float wl = valid ? (1.f - fr) : 0.f;
    float wh = valid ? fr : 0.f;
    if (isY) { s_ylo[j] = lo; s_yhi[j] = hi; s_wyl[j] = wl; s_wyh[j] = wh; }
    else     { s_xlo[j] = lo; s_xhi[j] = hi; s_wxl[j] = wl; s_wxh[j] = wh; }
  }
  __syncthreads();

  int cg = t & 63;          // channel group: channels cg*8 .. cg*8+7
  int pg = t >> 6;          // pixel stripe: pixels pg, pg+8, ...
  const u16* base = lf_t + (size_t)b * 1024 * CCH + cg * 8;

  for (int p = pg; p < 49; p += 8) {
    int py = p / 7, px = p % 7;
    v2f a0 = {0.f, 0.f}, a1 = {0.f, 0.f}, a2 = {0.f, 0.f}, a3 = {0.f, 0.f};
#pragma unroll
    for (int sy = 0; sy < 2; ++sy) {
      int jy = 2 * py + sy;
      const u16* rlo = base + s_ylo[jy] * 32 * CCH;
      const u16* rhi = base + s_yhi[jy] * 32 * CCH;
      float wyl = s_wyl[jy], wyh = s_wyh[jy];
#pragma unroll
      for (int sx = 0; sx < 2; ++sx) {
        int jx = 2 * px + sx;
        int xl = s_xlo[jx] * CCH, xh = s_xhi[jx] * CCH;
        v2f wll = {wyl * s_wxl[jx], wyl * s_wxl[jx]};
        v2f wlh = {wyl * s_wxh[jx], wyl * s_wxh[jx]};
        v2f whl = {wyh * s_wxl[jx], wyh * s_wxl[jx]};
        v2f whh = {wyh * s_wxh[jx], wyh * s_wxh[jx]};
        ushort8_t vll = *(const ushort8_t*)(rlo + xl);
        ushort8_t vlh = *(const ushort8_t*)(rlo + xh);
        ushort8_t vhl = *(const ushort8_t*)(rhi + xl);
        ushort8_t vhh = *(const ushort8_t*)(rhi + xh);
        a0 += wll * bf2x2(vll[0], vll[1]) + wlh * bf2x2(vlh[0], vlh[1])
            + whl * bf2x2(vhl[0], vhl[1]) + whh * bf2x2(vhh[0], vhh[1]);
        a1 += wll * bf2x2(vll[2], vll[3]) + wlh * bf2x2(vlh[2], vlh[3])
            + whl * bf2x2(vhl[2], vhl[3]) + whh * bf2x2(vhh[2], vhh[3]);
        a2 += wll * bf2x2(vll[4], vll[5]) + wlh * bf2x2(vlh[4], vlh[5])
            + whl * bf2x2(vhl[4], vhl[5]) + whh * bf2x2(vhh[4], vhh[5]);
        a3 += wll * bf2x2(vll[6], vll[7]) + wlh * bf2x2(vlh[6], vlh[7])
            + whl * bf2x2(vhl[6], vhl[7]) + whh * bf2x2(vhh[6], vhh[7]);
      }
    }
    int c0i = cg * 8;
    s_out[(c0i + 0) * 49 + p] = f2bf(a0.x * 0.25f);
    s_out[(c0i + 1) * 49 + p] = f2bf(a0.y * 0.25f);
    s_out[(c0i + 2) * 49 + p] = f2bf(a1.x * 0.25f);
    s_out[(c0i + 3) * 49 + p] = f2bf(a1.y * 0.25f);
    s_out[(c0i + 4) * 49 + p] = f2bf(a2.x * 0.25f);
    s_out[(c0i + 5) * 49 + p] = f2bf(a2.y * 0.25f);
    s_out[(c0i + 6) * 49 + p] = f2bf(a3.x * 0.25f);
    s_out[(c0i + 7) * 49 + p] = f2bf(a3.y * 0.25f);
  }
  __syncthreads();

  uint4* dst = (uint4*)(flat + (size_t)blk * INDIM);
  const uint4* src = (const uint4*)s_out;
  for (int i = t; i < INDIM / 8; i += 512) dst[i] = src[i];
}

// ---------------- kernel 4: GEMM, split-K, bf16 MFMA -----------------------
// v3: 128x64 tile (was 128x128) -> grid 8x5x28 = 1120 blocks = 4.4/CU.
// R2 post-mortem: per-kt critical path ~2600 cyc vs ~350 cyc of work — the
// vmcnt(0)+barrier drain was unhidden at 2.19 blocks/CU. 24 KB LDS keeps 5
// blocks resident; cross-block wave overlap (m114) hides the drain.
// XOR-swizzled LDS (R2) retained: conflicts stay 0.
__global__ __launch_bounds__(256) void k_gemm(const u16* __restrict__ flat,
                                              const u16* __restrict__ Wb,
                                              float* __restrict__ partials) {
  __shared__ u16 As[128 * 64];   // 16 KB
  __shared__ u16 Bs[64 * 64];    //  8 KB

  int tid = threadIdx.x;
  int wave = tid >> 6, lane = tid & 63;
  int wm = wave >> 1, wn = wave & 1;
  int quad = lane >> 4, r = lane & 15;
  int xb = r & 7;                       // read-side XOR key

  int tileM0 = blockIdx.y * 128;
  int tileN0 = blockIdx.x * 64;
  int kbase = blockIdx.z * (KITERS * 64);

  f32x4 acc[4][2];
#pragma unroll
  for (int mi = 0; mi < 4; ++mi)
#pragma unroll
    for (int ni = 0; ni < 2; ++ni) acc[mi][ni] = (f32x4){0.f, 0.f, 0.f, 0.f};

  for (int kt = 0; kt < KITERS; ++kt) {
    int k0 = kbase + kt * 64;
    // stage A: 1024 chunks of 16B, swizzled on the global side
#pragma unroll
    for (int t = 0; t < 4; ++t) {
      int chunk = (wave * 4 + t) * 64 + lane;
      int row = chunk >> 3;
      int pcol = chunk & 7;
      int lcol = ((pcol ^ (row & 7)) << 3);
      int grow = min(tileM0 + row, M_ROWS - 1);   // clamp M tail
      gload_lds16(flat + (size_t)grow * INDIM + k0 + lcol,
                  &As[(wave * 4 + t) * 512]);
    }
    // stage B: 512 chunks
#pragma unroll
    for (int t = 0; t < 2; ++t) {
      int chunk = (wave * 2 + t) * 64 + lane;
      int row = chunk >> 3;
      int pcol = chunk & 7;
      int lcol = ((pcol ^ (row & 7)) << 3);
      int nrow = tileN0 + row;
      gload_lds16(Wb + (size_t)nrow * INDIM + k0 + lcol,
                  &Bs[(wave * 2 + t) * 512]);
    }
    __syncthreads();

#pragma unroll
    for (int kk = 0; kk < 64; kk += 32) {
      int k8 = kk >> 3;                 // 0 or 4
      int pc = ((k8 + quad) ^ xb) << 3; // physical column (u16 units)
      short8 af[4], bfr[2];
#pragma unroll
      for (int mi = 0; mi < 4; ++mi)
        af[mi] = *(const short8*)&As[(wm * 64 + mi * 16 + r) * 64 + pc];
#pragma unroll
      for (int ni = 0; ni < 2; ++ni)
        bfr[ni] = *(const short8*)&Bs[(wn * 32 + ni * 16 + r) * 64 + pc];
#pragma unroll
      for (int mi = 0; mi < 4; ++mi)
#pragma unroll
        for (int ni = 0; ni < 2; ++ni)
          acc[mi][ni] = __builtin_amdgcn_mfma_f32_16x16x32_bf16(
              af[mi], bfr[ni], acc[mi][ni], 0, 0, 0);
    }
    __syncthreads();
  }

  float* part = partials + (size_t)blockIdx.z * (M_ROWS * HIDN);
#pragma unroll
  for (int mi = 0; mi < 4; ++mi)
#pragma unroll
    for (int ni = 0; ni < 2; ++ni) {
      int row0 = tileM0 + wm * 64 + mi * 16 + quad * 4;
      int col = tileN0 + wn * 32 + ni * 16 + r;
#pragma unroll
      for (int reg = 0; reg < 4; ++reg) {
        int row = row0 + reg;
        if (row < M_ROWS) part[(size_t)row * HIDN + col] = acc[mi][ni][reg];
      }
    }
}

// ---------------- kernel 5: reduce split-K + bias + relu -> feats f32 ------
__global__ __launch_bounds__(256) void k_reduce(const float* __restrict__ partials,
                                                const float* __restrict__ bias,
                                                float* __restrict__ feats) {
  int gid = blockIdx.x * 256 + threadIdx.x;   // < 576*512
  int h = gid & (HIDN - 1);
  float s = 0.f;
#pragma unroll
  for (int k = 0; k < KSPLIT; ++k) s += partials[(size_t)k * (M_ROWS * HIDN) + gid];
  s += bias[h];
  feats[gid] = fmaxf(s, 0.f);
}

// ---------------- kernel 6: all heads, one wave per output dot -------------
__device__ __forceinline__ float wave_red(float s) {
#pragma unroll
  for (int off = 32; off > 0; off >>= 1) s += __shfl_down(s, off);
  return s;
}

__device__ __forceinline__ float dot512(const float* __restrict__ f,
                                        const float* __restrict__ w, int lane) {
  const float4* f4 = (const float4*)f;
  const float4* w4 = (const float4*)w;
  float4 x0 = f4[lane], y0 = w4[lane];
  float4 x1 = f4[lane + 64], y1 = w4[lane + 64];
  return x0.x * y0.x + x0.y * y0.y + x0.z * y0.z + x0.w * y0.w +
         x1.x * y1.x + x1.y * y1.y + x1.z * y1.z + x1.w * y1.w;
}

__global__ __launch_bounds__(256) void k_heads(const float* __restrict__ feats,
                                               const float* __restrict__ pred,
                                               const float* __restrict__ cW,
                                               const float* __restrict__ cb,
                                               const float* __restrict__ pW,
                                               const float* __restrict__ pb,
                                               const float* __restrict__ lW,
                                               const float* __restrict__ lb,
                                               const float* __restrict__ gW,
                                               const float* __restrict__ gb,
                                               const int* __restrict__ lidx,
                                               const int* __restrict__ gidx,
                                               float* __restrict__ out) {
  int wid = blockIdx.x * 4 + (threadIdx.x >> 6);   // 0..4639
  int lane = threadIdx.x & 63;
  float sum = 0.f;

  if (wid < 1664) {                 // refined (B,26,4)
    int b = wid / 104, rr = wid % 104, s = rr >> 2, o = rr & 3;
    sum = dot512(feats + (size_t)(b * NBOX + s) * HIDN,
                 cW + (size_t)(s * 4 + o) * HIDN, lane);
    sum = wave_red(sum);
    if (lane == 0) {
      const float* p = pred + (size_t)(b * SS + s) * 4;
      float wdt = p[2] - p[0], hgt = p[3] - p[1];
      float whv = (o & 1) ? hgt : wdt;
      out[wid] = p[o] + (sum + cb[s * 4 + o]) * whv;
    }
  } else if (wid < 2080) {          // presence (B,26)
    int i = wid - 1664;
    int b = i / 26, s = i % 26;
    sum = dot512(feats + (size_t)(b * NBOX + s) * HIDN,
                 pW + (size_t)s * HIDN, lane);
    sum = wave_red(sum);
    if (lane == 0) out[1664 + i] = sum + pb[s];
  } else if (wid < 3616) {          // loc (B,12,8)
    int i = wid - 2080;
    int b = i / 96, rr = i % 96, l = rr >> 3, o = rr & 7;
    sum = dot512(feats + (size_t)(b * NBOX + lidx[l]) * HIDN,
                 lW + (size_t)(l * 8 + o) * HIDN, lane);
    sum = wave_red(sum);
    if (lane == 0) out[2080 + b * 160 + rr] = sum + lb[l * 8 + o];
  } else {                          // grp (B,4,16), K = 6*512
    int i = wid - 3616;
    int b = i / 64, rr = i % 64, g = rr >> 4, o = rr & 15;
    const float* w = gW + (size_t)(g * 16 + o) * 3072;
#pragma unroll
    for (int jj = 0; jj < 6; ++jj) {
      sum += dot512(feats + (size_t)(b * NBOX + gidx[g * 6 + jj]) * HIDN,
                    w + jj * 512, lane);
    }
    sum = wave_red(sum);
    if (lane == 0) out[2080 + b * 160 + 96 + rr] = sum + gb[g * 16 + o];
  }
}

// ---------------------------------------------------------------------------
extern "C" void kernel_launch(void* const* d_in, const int* in_sizes, int n_in,
                              void* d_out, int out_size, void* d_ws, size_t ws_size,
                              hipStream_t stream) {
  const float* lf      = (const float*)d_in[0];
  const float* pred    = (const float*)d_in[1];
  const float* roiW    = (const float*)d_in[2];
  const float* roiB    = (const float*)d_in[3];
  const float* cW      = (const float*)d_in[4];
  const float* cb      = (const float*)d_in[5];
  const float* pW      = (const float*)d_in[6];
  const float* pb      = (const float*)d_in[7];
  const float* lW      = (const float*)d_in[8];
  const float* lb      = (const float*)d_in[9];
  const float* gW      = (const float*)d_in[10];
  const float* gb      = (const float*)d_in[11];
  const int*   lidx    = (const int*)d_in[12];
  const int*   gidx    = (const int*)d_in[13];
  float* out = (float*)d_out;

  char* ws = (char*)d_ws;
  // region 0: lf_t (16.8 MB) then reused by partials (33.0 MB) after k_roi
  u16*   lf_t     = (u16*)ws;
  float* partials = (float*)ws;
  u16*   Wb   = (u16*)(ws + 33030144);                 // 25,690,112 B
  u16*   flat = (u16*)(ws + 33030144 + 25690112);      // 28,901,376 B
  float* feats = (float*)(ws + 33030144 + 25690112 + 28901376); // 1,179,648 B

  k_transpose_lf<<<dim3(32, 16, 16), dim3(32, 8), 0, stream>>>(lf, lf_t);
  k_convert_w<<<12544, 256, 0, stream>>>((const float4*)roiW, (ushort4*)Wb);
  k_roi<<<576, 512, 0, stream>>>(lf_t, pred, flat);
  // NOTE: partials aliases lf_t's region; k_roi (last reader of lf_t) is
  // stream-ordered before k_gemm (first writer of partials).
  k_gemm<<<dim3(8, 5, KSPLIT), 256, 0, stream>>>(flat, Wb, partials);
  k_reduce<<<(M_ROWS * HIDN) / 256, 256, 0, stream>>>(partials, roiB, feats);
  k_heads<<<1160, 256, 0, stream>>>(feats, pred, cW, cb, pW, pb, lW, lb, gW, gb,
                                    lidx, gidx, out);
}

// Round 5
// 221.008 us; speedup vs baseline: 1.0329x; 1.0189x over previous
//
#include <hip/hip_runtime.h>

typedef unsigned short u16;
typedef __attribute__((ext_vector_type(8))) short short8;
typedef __attribute__((ext_vector_type(8))) unsigned short ushort8_t;
typedef __attribute__((ext_vector_type(4))) float f32x4;
typedef __attribute__((ext_vector_type(2))) float v2f;

#define BATCH   16
#define CCH     512
#define NBOX    36
#define SS      26
#define INDIM   25088   // 512*49
#define HIDN    512
#define M_ROWS  576     // BATCH*NBOX
#define KSPLIT  28
#define KITERS  14      // per split, BK=64 -> 28*14*64 = 25088

__device__ __forceinline__ u16 f2bf(float f) {
  unsigned u = __float_as_uint(f);
  u += 0x7FFF + ((u >> 16) & 1);   // RNE
  return (u16)(u >> 16);
}
__device__ __forceinline__ float bf2f(u16 h) {
  return __uint_as_float(((unsigned)h) << 16);
}
__device__ __forceinline__ v2f bf2x2(u16 a, u16 b) {
  v2f r;
  r.x = __uint_as_float(((unsigned)a) << 16);
  r.y = __uint_as_float(((unsigned)b) << 16);
  return r;
}

// ---------------- kernel 1: transpose lf (B,C,H,W) f32 -> (B,HW,C) bf16 ----
// v2: 64c x 32x tile per block (one y row). Reads: 2x float4 per thread
// (128 B runs per plane row). Stores: ushort8 16 B per thread (v1 did 2 B
// scalar stores). LDS pad 66 -> write phase 2 lanes/bank (free).
__global__ __launch_bounds__(256) void k_transpose_lf(const float* __restrict__ in,
                                                      u16* __restrict__ out) {
  __shared__ u16 t[32][66];
  int b = blockIdx.z, y = blockIdx.y, ct = blockIdx.x;  // c0 = ct*64
  int tid = threadIdx.x;

  int cl = tid >> 2;            // 0..63 channel within tile
  int xq = (tid & 3) * 8;       // 8 consecutive x
  const float* src = in + ((size_t)(b * CCH + ct * 64 + cl) * 1024) + y * 32 + xq;
  float4 v0 = *(const float4*)src;
  float4 v1 = *(const float4*)(src + 4);
  t[xq + 0][cl] = f2bf(v0.x); t[xq + 1][cl] = f2bf(v0.y);
  t[xq + 2][cl] = f2bf(v0.z); t[xq + 3][cl] = f2bf(v0.w);
  t[xq + 4][cl] = f2bf(v1.x); t[xq + 5][cl] = f2bf(v1.y);
  t[xq + 6][cl] = f2bf(v1.z); t[xq + 7][cl] = f2bf(v1.w);
  __syncthreads();

  int xl = tid >> 3;            // 0..31
  int cq = (tid & 7) * 8;       // 8 consecutive channels
  ushort8_t o;
#pragma unroll
  for (int i = 0; i < 8; ++i) o[i] = t[xl][cq + i];
  *(ushort8_t*)(out + ((size_t)b * 1024 + y * 32 + xl) * CCH + ct * 64 + cq) = o;
}

// ---------------- kernel 2: roi_fc_W f32 -> bf16 ---------------------------
__global__ __launch_bounds__(256) void k_convert_w(const float4* __restrict__ in,
                                                   ushort4* __restrict__ out) {
  int i = blockIdx.x * 256 + threadIdx.x;   // grid sized exactly
  float4 v = in[i];
  ushort4 o;
  o.x = f2bf(v.x); o.y = f2bf(v.y); o.z = f2bf(v.z); o.w = f2bf(v.w);
  out[i] = o;
}

// ---------------- kernel 3: ROI align -> flat (576, 25088) bf16 ------------
// v3: v2f (packed-f32) accumulation -> v_pk_fma_f32. Thread = (cg: 8
// contiguous channels, pg: pixel stripe); 16B ushort8 tap loads; no spill.
__global__ __launch_bounds__(512) void k_roi(const u16* __restrict__ lf_t,
                                             const float* __restrict__ pred,
                                             u16* __restrict__ flat) {
  __shared__ int   s_ylo[14], s_yhi[14], s_xlo[14], s_xhi[14];
  __shared__ float s_wyl[14], s_wyh[14], s_wxl[14], s_wxh[14];
  __shared__ u16   s_out[INDIM];   // 50176 B

  int blk = blockIdx.x;
  int b = blk / NBOX, n = blk % NBOX;
  int t = threadIdx.x;

  if (t < 28) {
    bool isY = t < 14;
    int j = isY ? t : t - 14;
    float c0, c1, c2, c3;
    if (n < SS) {
      const float* p = pred + ((size_t)(b * SS + n)) * 4;
      c0 = p[0]; c1 = p[1]; c2 = p[2]; c3 = p[3];
    } else { c0 = 0.f; c1 = 0.f; c2 = 1.f; c3 = 1.f; }
    float lo1 = (isY ? c1 : c0) * 32.f;
    float hi1 = (isY ? c3 : c2) * 32.f;
    float sz = fmaxf(hi1 - lo1, 1.f);
    float bs = sz * (1.f / 7.f);
    float off = (float)(j >> 1) + 0.25f + 0.5f * (float)(j & 1);
    float pos = lo1 + off * bs;
    bool valid = (pos > -1.f) && (pos < 32.f);
    float tc = fminf(fmaxf(pos, 0.f), 31.f);
    int lo = (int)floorf(tc);
    int hi = min(lo + 1, 31);
    float fr = tc - (float)lo;
    float wl = valid ? (1.f - fr) : 0.f;
    float wh = valid ? fr : 0.f;
    if (isY) { s_ylo[j] = lo; s_yhi[j] = hi; s_wyl[j] = wl; s_wyh[j] = wh; }
    else     { s_xlo[j] = lo; s_xhi[j] = hi; s_wxl[j] = wl; s_wxh[j] = wh; }
  }
  __syncthreads();

  int cg = t & 63;          // channel group: channels cg*8 .. cg*8+7
  int pg = t >> 6;          // pixel stripe: pixels pg, pg+8, ...
  const u16* base = lf_t + (size_t)b * 1024 * CCH + cg * 8;

  for (int p = pg; p < 49; p += 8) {
    int py = p / 7, px = p % 7;
    v2f a0 = {0.f, 0.f}, a1 = {0.f, 0.f}, a2 = {0.f, 0.f}, a3 = {0.f, 0.f};
#pragma unroll
    for (int sy = 0; sy < 2; ++sy) {
      int jy = 2 * py + sy;
      const u16* rlo = base + s_ylo[jy] * 32 * CCH;
      const u16* rhi = base + s_yhi[jy] * 32 * CCH;
      float wyl = s_wyl[jy], wyh = s_wyh[jy];
#pragma unroll
      for (int sx = 0; sx < 2; ++sx) {
        int jx = 2 * px + sx;
        int xl = s_xlo[jx] * CCH, xh = s_xhi[jx] * CCH;
        v2f wll = {wyl * s_wxl[jx], wyl * s_wxl[jx]};
        v2f wlh = {wyl * s_wxh[jx], wyl * s_wxh[jx]};
        v2f whl = {wyh * s_wxl[jx], wyh * s_wxl[jx]};
        v2f whh = {wyh * s_wxh[jx], wyh * s_wxh[jx]};
        ushort8_t vll = *(const ushort8_t*)(rlo + xl);
        ushort8_t vlh = *(const ushort8_t*)(rlo + xh);
        ushort8_t vhl = *(const ushort8_t*)(rhi + xl);
        ushort8_t vhh = *(const ushort8_t*)(rhi + xh);
        a0 += wll * bf2x2(vll[0], vll[1]) + wlh * bf2x2(vlh[0], vlh[1])
            + whl * bf2x2(vhl[0], vhl[1]) + whh * bf2x2(vhh[0], vhh[1]);
        a1 += wll * bf2x2(vll[2], vll[3]) + wlh * bf2x2(vlh[2], vlh[3])
            + whl * bf2x2(vhl[2], vhl[3]) + whh * bf2x2(vhh[2], vhh[3]);
        a2 += wll * bf2x2(vll[4], vll[5]) + wlh * bf2x2(vlh[4], vlh[5])
            + whl * bf2x2(vhl[4], vhl[5]) + whh * bf2x2(vhh[4], vhh[5]);
        a3 += wll * bf2x2(vll[6], vll[7]) + wlh * bf2x2(vlh[6], vlh[7])
            + whl * bf2x2(vhl[6], vhl[7]) + whh * bf2x2(vhh[6], vhh[7]);
      }
    }
    int c0i = cg * 8;
    s_out[(c0i + 0) * 49 + p] = f2bf(a0.x * 0.25f);
    s_out[(c0i + 1) * 49 + p] = f2bf(a0.y * 0.25f);
    s_out[(c0i + 2) * 49 + p] = f2bf(a1.x * 0.25f);
    s_out[(c0i + 3) * 49 + p] = f2bf(a1.y * 0.25f);
    s_out[(c0i + 4) * 49 + p] = f2bf(a2.x * 0.25f);
    s_out[(c0i + 5) * 49 + p] = f2bf(a2.y * 0.25f);
    s_out[(c0i + 6) * 49 + p] = f2bf(a3.x * 0.25f);
    s_out[(c0i + 7) * 49 + p] = f2bf(a3.y * 0.25f);
  }
  __syncthreads();

  uint4* dst = (uint4*)(flat + (size_t)blk * INDIM);
  const uint4* src = (const uint4*)s_out;
  for (int i = t; i < INDIM / 8; i += 512) dst[i] = src[i];
}

// ---------------- kernel 4: GEMM, split-K, bf16 MFMA -----------------------
// v4: restructured K-loop — software pipeline via REGISTER staging.
// R2-R4 evidence: global_load_lds forces s_waitcnt vmcnt(0) before s_barrier
// (full L2/HBM latency serialized into every kt; ~2600 cyc/kt vs ~350 work).
// Now: global->VGPR loads for tile kt+1 are issued BEFORE the compute phase
// of tile kt and stay in flight across the barrier (register loads need no
// drain there); the vmcnt wait lands at the next ds_write, after ~1 compute
// phase of overlap. 128x128 tile (lowest-traffic config), KSPLIT=28.
// XOR swizzle now applied on the ds_write side (free per-lane scatter).
__global__ __launch_bounds__(256) void k_gemm(const u16* __restrict__ flat,
                                              const u16* __restrict__ Wb,
                                              float* __restrict__ partials) {
  __shared__ u16 As[128 * 64];   // 16 KB
  __shared__ u16 Bs[128 * 64];   // 16 KB

  int tid = threadIdx.x;
  int wave = tid >> 6, lane = tid & 63;
  int wm = wave >> 1, wn = wave & 1;
  int quad = lane >> 4, r = lane & 15;
  int xb = r & 7;                       // read-side XOR key

  int tileM0 = blockIdx.y * 128;
  int tileN0 = blockIdx.x * 128;
  int kbase = blockIdx.z * (KITERS * 64);

  // Per-thread staging map: 4 16B chunks each for A and B.
  // chunk = (wave*4+t)*64 + lane; row = chunk>>3; lc = chunk&7 (logical col)
  // LDS phys col = lc ^ (row&7)  (bank swizzle)
  size_t aoff[4], boff[4];
  int    ldso[4];
#pragma unroll
  for (int t = 0; t < 4; ++t) {
    int chunk = (wave * 4 + t) * 64 + lane;
    int row = chunk >> 3;
    int lc = chunk & 7;
    ldso[t] = row * 64 + ((lc ^ (row & 7)) << 3);
    int grow = min(tileM0 + row, M_ROWS - 1);     // clamp M tail
    aoff[t] = (size_t)grow * INDIM + kbase + lc * 8;
    boff[t] = (size_t)(tileN0 + row) * INDIM + kbase + lc * 8;
  }

  f32x4 acc[4][4];
#pragma unroll
  for (int mi = 0; mi < 4; ++mi)
#pragma unroll
    for (int ni = 0; ni < 4; ++ni) acc[mi][ni] = (f32x4){0.f, 0.f, 0.f, 0.f};

  short8 ra[4], rb[4];
  // prologue: load tile 0 into registers
#pragma unroll
  for (int t = 0; t < 4; ++t) {
    ra[t] = *(const short8*)(flat + aoff[t]);
    rb[t] = *(const short8*)(Wb + boff[t]);
  }

  for (int kt = 0; kt < KITERS; ++kt) {
    // commit current registers to LDS (vmcnt wait lands here, overlapped)
#pragma unroll
    for (int t = 0; t < 4; ++t) {
      *(short8*)&As[ldso[t]] = ra[t];
      *(short8*)&Bs[ldso[t]] = rb[t];
    }
    __syncthreads();

    // issue next tile's global loads (stay in flight through compute)
    if (kt + 1 < KITERS) {
      int kadv = (kt + 1) * 64;
#pragma unroll
      for (int t = 0; t < 4; ++t) {
        ra[t] = *(const short8*)(flat + aoff[t] + kadv);
        rb[t] = *(const short8*)(Wb + boff[t] + kadv);
      }
    }

    // compute on the committed tile
#pragma unroll
    for (int kk = 0; kk < 64; kk += 32) {
      int k8 = kk >> 3;                 // 0 or 4
      int pc = ((k8 + quad) ^ xb) << 3; // physical column (u16 units)
      short8 af[4], bfr[4];
#pragma unroll
      for (int mi = 0; mi < 4; ++mi)
        af[mi] = *(const short8*)&As[(wm * 64 + mi * 16 + r) * 64 + pc];
#pragma unroll
      for (int ni = 0; ni < 4; ++ni)
        bfr[ni] = *(const short8*)&Bs[(wn * 64 + ni * 16 + r) * 64 + pc];
#pragma unroll
      for (int mi = 0; mi < 4; ++mi)
#pragma unroll
        for (int ni = 0; ni < 4; ++ni)
          acc[mi][ni] = __builtin_amdgcn_mfma_f32_16x16x32_bf16(
              af[mi], bfr[ni], acc[mi][ni], 0, 0, 0);
    }
    __syncthreads();
  }

  float* part = partials + (size_t)blockIdx.z * (M_ROWS * HIDN);
#pragma unroll
  for (int mi = 0; mi < 4; ++mi)
#pragma unroll
    for (int ni = 0; ni < 4; ++ni) {
      int row0 = tileM0 + wm * 64 + mi * 16 + quad * 4;
      int col = tileN0 + wn * 64 + ni * 16 + r;
#pragma unroll
      for (int reg = 0; reg < 4; ++reg) {
        int row = row0 + reg;
        if (row < M_ROWS) part[(size_t)row * HIDN + col] = acc[mi][ni][reg];
      }
    }
}

// ---------------- kernel 5: reduce split-K + bias + relu -> feats f32 ------
__global__ __launch_bounds__(256) void k_reduce(const float4* __restrict__ partials,
                                                const float* __restrict__ bias,
                                                float4* __restrict__ feats) {
  int gid = blockIdx.x * 256 + threadIdx.x;   // < 576*512/4
  int h4 = gid & (HIDN / 4 - 1);
  float4 s = {0.f, 0.f, 0.f, 0.f};
#pragma unroll
  for (int k = 0; k < KSPLIT; ++k) {
    float4 v = partials[(size_t)k * (M_ROWS * HIDN / 4) + gid];
    s.x += v.x; s.y += v.y; s.z += v.z; s.w += v.w;
  }
  const float* bi = bias + h4 * 4;
  s.x = fmaxf(s.x + bi[0], 0.f);
  s.y = fmaxf(s.y + bi[1], 0.f);
  s.z = fmaxf(s.z + bi[2], 0.f);
  s.w = fmaxf(s.w + bi[3], 0.f);
  feats[gid] = s;
}

// ---------------- kernel 6: all heads, one wave per output dot -------------
__device__ __forceinline__ float wave_red(float s) {
#pragma unroll
  for (int off = 32; off > 0; off >>= 1) s += __shfl_down(s, off);
  return s;
}

__device__ __forceinline__ float dot512(const float* __restrict__ f,
                                        const float* __restrict__ w, int lane) {
  const float4* f4 = (const float4*)f;
  const float4* w4 = (const float4*)w;
  float4 x0 = f4[lane], y0 = w4[lane];
  float4 x1 = f4[lane + 64], y1 = w4[lane + 64];
  return x0.x * y0.x + x0.y * y0.y + x0.z * y0.z + x0.w * y0.w +
         x1.x * y1.x + x1.y * y1.y + x1.z * y1.z + x1.w * y1.w;
}

__global__ __launch_bounds__(256) void k_heads(const float* __restrict__ feats,
                                               const float* __restrict__ pred,
                                               const float* __restrict__ cW,
                                               const float* __restrict__ cb,
                                               const float* __restrict__ pW,
                                               const float* __restrict__ pb,
                                               const float* __restrict__ lW,
                                               const float* __restrict__ lb,
                                               const float* __restrict__ gW,
                                               const float* __restrict__ gb,
                                               const int* __restrict__ lidx,
                                               const int* __restrict__ gidx,
                                               float* __restrict__ out) {
  int wid = blockIdx.x * 4 + (threadIdx.x >> 6);   // 0..4639
  int lane = threadIdx.x & 63;
  float sum = 0.f;

  if (wid < 1664) {                 // refined (B,26,4)
    int b = wid / 104, rr = wid % 104, s = rr >> 2, o = rr & 3;
    sum = dot512(feats + (size_t)(b * NBOX + s) * HIDN,
                 cW + (size_t)(s * 4 + o) * HIDN, lane);
    sum = wave_red(sum);
    if (lane == 0) {
      const float* p = pred + (size_t)(b * SS + s) * 4;
      float wdt = p[2] - p[0], hgt = p[3] - p[1];
      float whv = (o & 1) ? hgt : wdt;
      out[wid] = p[o] + (sum + cb[s * 4 + o]) * whv;
    }
  } else if (wid < 2080) {          // presence (B,26)
    int i = wid - 1664;
    int b = i / 26, s = i % 26;
    sum = dot512(feats + (size_t)(b * NBOX + s) * HIDN,
                 pW + (size_t)s * HIDN, lane);
    sum = wave_red(sum);
    if (lane == 0) out[1664 + i] = sum + pb[s];
  } else if (wid < 3616) {          // loc (B,12,8)
    int i = wid - 2080;
    int b = i / 96, rr = i % 96, l = rr >> 3, o = rr & 7;
    sum = dot512(feats + (size_t)(b * NBOX + lidx[l]) * HIDN,
                 lW + (size_t)(l * 8 + o) * HIDN, lane);
    sum = wave_red(sum);
    if (lane == 0) out[2080 + b * 160 + rr] = sum + lb[l * 8 + o];
  } else {                          // grp (B,4,16), K = 6*512
    int i = wid - 3616;
    int b = i / 64, rr = i % 64, g = rr >> 4, o = rr & 15;
    const float* w = gW + (size_t)(g * 16 + o) * 3072;
#pragma unroll
    for (int jj = 0; jj < 6; ++jj) {
      sum += dot512(feats + (size_t)(b * NBOX + gidx[g * 6 + jj]) * HIDN,
                    w + jj * 512, lane);
    }
    sum = wave_red(sum);
    if (lane == 0) out[2080 + b * 160 + 96 + rr] = sum + gb[g * 16 + o];
  }
}

// ---------------------------------------------------------------------------
extern "C" void kernel_launch(void* const* d_in, const int* in_sizes, int n_in,
                              void* d_out, int out_size, void* d_ws, size_t ws_size,
                              hipStream_t stream) {
  const float* lf      = (const float*)d_in[0];
  const float* pred    = (const float*)d_in[1];
  const float* roiW    = (const float*)d_in[2];
  const float* roiB    = (const float*)d_in[3];
  const float* cW      = (const float*)d_in[4];
  const float* cb      = (const float*)d_in[5];
  const float* pW      = (const float*)d_in[6];
  const float* pb      = (const float*)d_in[7];
  const float* lW      = (const float*)d_in[8];
  const float* lb      = (const float*)d_in[9];
  const float* gW      = (const float*)d_in[10];
  const float* gb      = (const float*)d_in[11];
  const int*   lidx    = (const int*)d_in[12];
  const int*   gidx    = (const int*)d_in[13];
  float* out = (float*)d_out;

  char* ws = (char*)d_ws;
  // region 0: lf_t (16.8 MB) then reused by partials (33.0 MB) after k_roi
  u16*   lf_t     = (u16*)ws;
  float* partials = (float*)ws;
  u16*   Wb   = (u16*)(ws + 33030144);                 // 25,690,112 B
  u16*   flat = (u16*)(ws + 33030144 + 25690112);      // 28,901,376 B
  float* feats = (float*)(ws + 33030144 + 25690112 + 28901376); // 1,179,648 B

  k_transpose_lf<<<dim3(8, 32, 16), 256, 0, stream>>>(lf, lf_t);
  k_convert_w<<<12544, 256, 0, stream>>>((const float4*)roiW, (ushort4*)Wb);
  k_roi<<<576, 512, 0, stream>>>(lf_t, pred, flat);
  // NOTE: partials aliases lf_t's region; k_roi (last reader of lf_t) is
  // stream-ordered before k_gemm (first writer of partials).
  k_gemm<<<dim3(4, 5, KSPLIT), 256, 0, stream>>>(flat, Wb, partials);
  k_reduce<<<(M_ROWS * HIDN / 4) / 256, 256, 0, stream>>>(
      (const float4*)partials, roiB, (float4*)feats);
  k_heads<<<1160, 256, 0, stream>>>(feats, pred, cW, cb, pW, pb, lW, lb, gW, gb,
                                    lidx, gidx, out);
}